// Round 10
// baseline (290.540 us; speedup 1.0000x reference)
//
#include <hip/hip_runtime.h>

#define NHEAD 12
#define BATCH 8
#define SEQ 1024
#define LOG2E 1.4426950408889634f

typedef __bf16 bf16x8 __attribute__((ext_vector_type(8)));
typedef float  f32x4  __attribute__((ext_vector_type(4)));

// Manual DMA-completion discipline (global_load_lds is vmcnt-tracked; with
// distinct __shared__ symbols the compiler emits NO waits itself - R8 race).
// VMWAIT(N): wait until <= N vmem ops outstanding ("oldest first" - m135).
#define VMWAIT(N) asm volatile("s_waitcnt vmcnt(" #N ")" ::: "memory")

__device__ __forceinline__ unsigned short f2bf(float f) {
    union { float f; unsigned u; } v; v.f = f;
    unsigned u = v.u;
    u += 0x7fff + ((u >> 16) & 1);   // RNE
    return (unsigned short)(u >> 16);
}

__device__ __forceinline__ void gload_lds16(const void* g, void* l) {
    __builtin_amdgcn_global_load_lds(
        (const __attribute__((address_space(1))) unsigned*)g,
        (__attribute__((address_space(3))) unsigned*)l, 16, 0, 0);
}

// region sizes (floats)
#define SZ_X    6291456
#define SZ_QKVW 1769472
#define SZ_PW   589824
#define CONV_TOTAL 15532032   // x + pos + qkv_w + pq_w + pk_w

// ---------------------------------------------------------------------------
// Kernel 0: convert fp32 inputs/weights -> bf16 in workspace (once).
// ---------------------------------------------------------------------------
__global__ __launch_bounds__(256) void convert_kernel(
    const float* __restrict__ x, const float* __restrict__ pos,
    const float* __restrict__ qkv_w, const float* __restrict__ pq_w,
    const float* __restrict__ pk_w, unsigned short* __restrict__ dst)
{
    const size_t i4 = ((size_t)blockIdx.x * 256 + threadIdx.x) * 4;
    if (i4 >= CONV_TOTAL) return;
    const float* src; size_t off;
    if (i4 < SZ_X)                { src = x;     off = i4; }
    else if (i4 < 2 * SZ_X)       { src = pos;   off = i4 - SZ_X; }
    else if (i4 < 2 * SZ_X + SZ_QKVW) { src = qkv_w; off = i4 - 2 * SZ_X; }
    else if (i4 < 2 * SZ_X + SZ_QKVW + SZ_PW) { src = pq_w; off = i4 - 2 * SZ_X - SZ_QKVW; }
    else                          { src = pk_w;  off = i4 - 2 * SZ_X - SZ_QKVW - SZ_PW; }
    float4 v = *(const float4*)(src + off);
    ushort4 o;
    o.x = f2bf(v.x); o.y = f2bf(v.y); o.z = f2bf(v.z); o.w = f2bf(v.w);
    *(ushort4*)(dst + i4) = o;
}

// ---------------------------------------------------------------------------
// Kernel 1: fused projection GEMM, 128x128x32, 256 threads (4 waves x 64x64).
// QUAD-buffered LDS (4 distinct symbol sets), prefetch distance 3, manual
// vmcnt(8) waits (4 loads/thread/stage; leave 2 stages in flight).  R9 showed
// depth-1 prefetch exposes ~700 cyc of HBM latency per iter; depth-3 covers it.
// Q2 (g0,g1) scaled by LOG2E so attn uses exp2 directly.
// grid = (cb*8, 30), n-tiles remapped so g3 (K=1536) dispatches first.
// ---------------------------------------------------------------------------

#define PROJ_STAGE(K0, AS, BS) do {                                          \
    const int k0_ = (K0);                                                    \
    const unsigned short* asrc_; int acol_;                                  \
    if (g == 4)                    { asrc_ = posb; acol_ = k0_; }            \
    else if (g == 3 && k0_ >= 768) { asrc_ = posb; acol_ = k0_ - 768; }      \
    else                           { asrc_ = xb;   acol_ = k0_; }            \
    gload_lds16(asrc_ + (size_t)(m0 + r0) * 768 + acol_ + q0 * 8, &AS[base0]);\
    gload_lds16(asrc_ + (size_t)(m0 + r1) * 768 + acol_ + q1 * 8, &AS[base1]);\
    const unsigned short* wsrc_; int wro_, wco_;                             \
    if (g <= 2)       { wsrc_ = qkvw; wro_ = n0;        wco_ = k0_; }        \
    else if (g == 3) {                                                       \
        if (k0_ < 768) { wsrc_ = qkvw; wro_ = n0 - 1536; wco_ = k0_; }       \
        else           { wsrc_ = pqw;  wro_ = n0 - 2304; wco_ = k0_ - 768; } \
    } else            { wsrc_ = pkw;  wro_ = n0 - 3072; wco_ = k0_; }        \
    gload_lds16(wsrc_ + (size_t)(wro_ + r0) * 768 + wco_ + q0 * 8, &BS[base0]);\
    gload_lds16(wsrc_ + (size_t)(wro_ + r1) * 768 + wco_ + q1 * 8, &BS[base1]);\
} while (0)

#define PROJ_COMPUTE(AS, BS) do {                                            \
    bf16x8 af[4], bfr[4];                                                    \
    _Pragma("unroll")                                                        \
    for (int mt = 0; mt < 4; ++mt) {                                         \
        const int rr = wm + mt * 16 + col16;                                 \
        af[mt] = *(const bf16x8*)&AS[rr * 32 + ((quad ^ ((rr >> 1) & 3)) * 8)];\
    }                                                                        \
    _Pragma("unroll")                                                        \
    for (int nt = 0; nt < 4; ++nt) {                                         \
        const int rr = wn + nt * 16 + col16;                                 \
        bfr[nt] = *(const bf16x8*)&BS[rr * 32 + ((quad ^ ((rr >> 1) & 3)) * 8)];\
    }                                                                        \
    _Pragma("unroll")                                                        \
    for (int mt = 0; mt < 4; ++mt)                                           \
        _Pragma("unroll")                                                    \
        for (int nt = 0; nt < 4; ++nt)                                       \
            acc[mt][nt] = __builtin_amdgcn_mfma_f32_16x16x32_bf16(           \
                af[mt], bfr[nt], acc[mt][nt], 0, 0, 0);                      \
} while (0)

__global__ __launch_bounds__(256) void proj_kernel(
    const unsigned short* __restrict__ xb, const unsigned short* __restrict__ posb,
    const unsigned short* __restrict__ qkvw, const unsigned short* __restrict__ pqw,
    const unsigned short* __restrict__ pkw,
    const float* __restrict__ qkv_b, const float* __restrict__ pq_b,
    const float* __restrict__ pk_b,
    unsigned short* __restrict__ Q2, unsigned short* __restrict__ K2,
    unsigned short* __restrict__ Vt)
{
    __shared__ unsigned short As0[128 * 32];
    __shared__ unsigned short As1[128 * 32];
    __shared__ unsigned short As2[128 * 32];
    __shared__ unsigned short As3[128 * 32];
    __shared__ unsigned short Bs0[128 * 32];
    __shared__ unsigned short Bs1[128 * 32];
    __shared__ unsigned short Bs2[128 * 32];
    __shared__ unsigned short Bs3[128 * 32];

    const int m0 = blockIdx.x * 128;
    const int nt30 = ((int)blockIdx.y + 18) % 30;   // g3 tiles (18..23) first
    const int n0 = nt30 * 128;
    const int g  = n0 / 768;
    const int nk = (g == 3) ? 48 : 24;              // both == 0 (mod 4), >= 8

    const int tid   = threadIdx.x;
    const int lane  = tid & 63;
    const int w     = tid >> 6;
    const int wm    = (w & 1) * 64;
    const int wn    = (w >> 1) * 64;
    const int quad  = lane >> 4;
    const int col16 = lane & 15;

    // staging: 512 chunks of 16B per tile; thread handles chunks c0, c1.
    // chunk c -> row r=c>>2, LDS slot s=c&3 holds global k-seg s^((r>>1)&3).
    const int c0 = w * 64 + lane;
    const int c1 = c0 + 256;
    const int r0 = c0 >> 2, q0 = (c0 & 3) ^ ((c0 >> 3) & 3);
    const int r1 = c1 >> 2, q1 = (c1 & 3) ^ ((c1 >> 3) & 3);
    const int base0 = (w * 64) * 8;          // wave-uniform LDS short offsets
    const int base1 = (w * 64 + 256) * 8;

    f32x4 acc[4][4];
    const f32x4 fzero = {0.f, 0.f, 0.f, 0.f};
#pragma unroll
    for (int mt = 0; mt < 4; ++mt)
#pragma unroll
        for (int nt = 0; nt < 4; ++nt) acc[mt][nt] = fzero;

    // prologue: stages 0,1,2 -> bufs 0,1,2 (12 loads/thread outstanding)
    PROJ_STAGE(0,  As0, Bs0);
    PROJ_STAGE(32, As1, Bs1);
    PROJ_STAGE(64, As2, Bs2);

    // main: trips of 4 stages; invariant at sub-iter for stage s:
    //   outstanding = stages s, s+1, s+2 (12 loads) -> VMWAIT(8) completes s.
    for (int s = 0; s < nk - 4; s += 4) {
        VMWAIT(8); __syncthreads();
        PROJ_STAGE((s + 3) * 32, As3, Bs3); PROJ_COMPUTE(As0, Bs0);
        VMWAIT(8); __syncthreads();
        PROJ_STAGE((s + 4) * 32, As0, Bs0); PROJ_COMPUTE(As1, Bs1);
        VMWAIT(8); __syncthreads();
        PROJ_STAGE((s + 5) * 32, As1, Bs1); PROJ_COMPUTE(As2, Bs2);
        VMWAIT(8); __syncthreads();
        PROJ_STAGE((s + 6) * 32, As2, Bs2); PROJ_COMPUTE(As3, Bs3);
    }
    // epilogue: stages nk-4..nk-1 (bufs 0..3); waits 8,8,4,0
    VMWAIT(8); __syncthreads();
    PROJ_STAGE((nk - 1) * 32, As3, Bs3); PROJ_COMPUTE(As0, Bs0);
    VMWAIT(8); __syncthreads(); PROJ_COMPUTE(As1, Bs1);
    VMWAIT(4); __syncthreads(); PROJ_COMPUTE(As2, Bs2);
    VMWAIT(0); __syncthreads(); PROJ_COMPUTE(As3, Bs3);

    // ---- epilogue: C/D layout col=lane&15, row=quad*4+reg
#pragma unroll
    for (int mt = 0; mt < 4; ++mt) {
        const int mbase = m0 + wm + mt * 16 + quad * 4;
#pragma unroll
        for (int nt = 0; nt < 4; ++nt) {
            const int n = n0 + wn + nt * 16 + col16;
            if (g == 2) {
                // packed: 4 consecutive l per lane -> one 8B store
                const int b = mbase >> 10, l0 = mbase & 1023;
                const int c = n - 1536, h = c >> 6, dd = c & 63;
                ushort4 pk;
                pk.x = f2bf(acc[mt][nt][0] + qkv_b[n]);
                pk.y = f2bf(acc[mt][nt][1] + qkv_b[n]);
                pk.z = f2bf(acc[mt][nt][2] + qkv_b[n]);
                pk.w = f2bf(acc[mt][nt][3] + qkv_b[n]);
                *(ushort4*)&Vt[((size_t)(b * NHEAD + h) * 64 + dd) * 1024 + l0] = pk;
                continue;
            }
#pragma unroll
            for (int r = 0; r < 4; ++r) {
                const int m = mbase + r;
                const int b = m >> 10, l = m & 1023;   // chunk-local b
                float val = acc[mt][nt][r];
                if (g == 0) {
                    val = (val + qkv_b[n]) * LOG2E;
                    const int h = n >> 6, dd = n & 63;
                    Q2[((size_t)(b * NHEAD + h) * 1024 + l) * 128 + dd] = f2bf(val);
                } else if (g == 1) {
                    val = (val + qkv_b[n]) * (LOG2E / 48.0f);
                    const int c = n - 768, h = c >> 6, dd = c & 63;
                    Q2[((size_t)(b * NHEAD + h) * 1024 + l) * 128 + 64 + dd] = f2bf(val);
                } else if (g == 3) {
                    const int c = n - 2304;
                    val += qkv_b[n - 1536] + pq_b[c];
                    const int h = c >> 6, dd = c & 63;
                    K2[((size_t)(b * NHEAD + h) * 1024 + l) * 128 + dd] = f2bf(val);
                } else {
                    const int c = n - 3072;
                    val += pk_b[c];
                    const int h = c >> 6, dd = c & 63;
                    K2[((size_t)(b * NHEAD + h) * 1024 + l) * 128 + 64 + dd] = f2bf(val);
                }
            }
        }
    }
}

// ---------------------------------------------------------------------------
// Kernel 2: flash attention, transposed-S, exp2 softmax (log2e pre-folded
// into Q2).  Quad-buffered K2s/Vts, prefetch distance 3, manual vmcnt(6)
// (3 loads/thread/stage).  256 thr (4 waves x 32 q), grid = (cb*12, 8).
// ---------------------------------------------------------------------------

#define ATTN_STAGE(J0, KS, VS) do {                                          \
    const int j0_ = (J0);                                                    \
    gload_lds16(&K2[q2base + (size_t)(j0_ + kr0) * 128 + kc0 * 8], &KS[kbase0]);\
    gload_lds16(&K2[q2base + (size_t)(j0_ + kr1) * 128 + kc1 * 8], &KS[kbase1]);\
    gload_lds16(&Vt[vtbase + (size_t)vr * 1024 + j0_ + vc * 8],    &VS[vbase]);\
} while (0)

#define ATTN_COMPUTE(KS, VS) do {                                            \
    f32x4 st[2][2] = {{fzero, fzero}, {fzero, fzero}};                       \
    _Pragma("unroll")                                                        \
    for (int kk = 0; kk < 4; ++kk) {                                         \
        const int rrj0 = col16, rrj1 = 16 + col16;                           \
        bf16x8 kf0 = *(const bf16x8*)&KS[rrj0 * 128 + (((kk * 4 + quad) ^ (rrj0 & 15)) * 8)];\
        bf16x8 kf1 = *(const bf16x8*)&KS[rrj1 * 128 + (((kk * 4 + quad) ^ (rrj1 & 15)) * 8)];\
        _Pragma("unroll")                                                    \
        for (int qt = 0; qt < 2; ++qt) {                                     \
            st[0][qt] = __builtin_amdgcn_mfma_f32_16x16x32_bf16(kf0, bq[qt][kk], st[0][qt], 0, 0, 0);\
            st[1][qt] = __builtin_amdgcn_mfma_f32_16x16x32_bf16(kf1, bq[qt][kk], st[1][qt], 0, 0, 0);\
        }                                                                    \
    }                                                                        \
    _Pragma("unroll")                                                        \
    for (int qt = 0; qt < 2; ++qt) {                                         \
        float p0[4], p1[4], s = 0.f;                                         \
        _Pragma("unroll")                                                    \
        for (int r = 0; r < 4; ++r) {                                        \
            p0[r] = __builtin_amdgcn_exp2f(st[0][qt][r]);                    \
            p1[r] = __builtin_amdgcn_exp2f(st[1][qt][r]);                    \
            s += p0[r] + p1[r];                                              \
        }                                                                    \
        lsum[qt] += s;                                                       \
        ushort4 pk0, pk1;                                                    \
        pk0.x = f2bf(p0[0]); pk0.y = f2bf(p0[1]); pk0.z = f2bf(p0[2]); pk0.w = f2bf(p0[3]);\
        pk1.x = f2bf(p1[0]); pk1.y = f2bf(p1[1]); pk1.z = f2bf(p1[2]); pk1.w = f2bf(p1[3]);\
        *(ushort4*)&Ps[w][qt * 16 + col16][quad * 4]      = pk0;             \
        *(ushort4*)&Ps[w][qt * 16 + col16][16 + quad * 4] = pk1;             \
    }                                                                        \
    bf16x8 bp[2];                                                            \
    bp[0] = *(const bf16x8*)&Ps[w][col16][quad * 8];                         \
    bp[1] = *(const bf16x8*)&Ps[w][16 + col16][quad * 8];                    \
    _Pragma("unroll")                                                        \
    for (int c2 = 0; c2 < 4; ++c2) {                                         \
        const int rv = c2 * 16 + col16;                                      \
        bf16x8 av = *(const bf16x8*)&VS[rv * 32 + ((quad ^ ((rv >> 2) & 3)) * 8)];\
        _Pragma("unroll")                                                    \
        for (int qt = 0; qt < 2; ++qt)                                       \
            o[qt][c2] = __builtin_amdgcn_mfma_f32_16x16x32_bf16(av, bp[qt], o[qt][c2], 0, 0, 0);\
    }                                                                        \
} while (0)

__global__ __launch_bounds__(256) void attn_kernel(
    const unsigned short* __restrict__ Q2, const unsigned short* __restrict__ K2,
    const unsigned short* __restrict__ Vt, float* __restrict__ out, int b0)
{
    __shared__ unsigned short K2sA[32 * 128];
    __shared__ unsigned short K2sB[32 * 128];
    __shared__ unsigned short K2sC[32 * 128];
    __shared__ unsigned short K2sD[32 * 128];
    __shared__ unsigned short VtsA[64 * 32];
    __shared__ unsigned short VtsB[64 * 32];
    __shared__ unsigned short VtsC[64 * 32];
    __shared__ unsigned short VtsD[64 * 32];
    __shared__ unsigned short Ps[4][32][40];      // per-wave P[q_local][j] (+8 pad)

    const int bh_l = blockIdx.x;
    const int b = b0 + bh_l / NHEAD, h = bh_l % NHEAD;
    const int tid   = threadIdx.x;
    const int lane  = tid & 63;
    const int w     = tid >> 6;
    const int quad  = lane >> 4;
    const int col16 = lane & 15;
    const int qbase = blockIdx.y * 128 + w * 32;

    const size_t q2base = (size_t)bh_l * 1024 * 128;
    const size_t vtbase = (size_t)bh_l * 64 * 1024;

    // staging chunk ids (16B).  K2: 512 chunks (2/thread); Vt: 256 (1/thread).
    // LDS chunk L holds global k-seg (L&15)^(r&15) [K2] / (L&3)^((L>>4)&3) [Vt].
    const int kL0 = w * 64 + lane, kL1 = kL0 + 256;
    const int kr0 = kL0 >> 4, kc0 = (kL0 & 15) ^ (kr0 & 15);
    const int kr1 = kL1 >> 4, kc1 = (kL1 & 15) ^ (kr1 & 15);
    const int vL  = w * 64 + lane;
    const int vr  = vL >> 2,  vc  = (vL & 3) ^ ((vL >> 4) & 3);
    const int kbase0 = (w * 64) * 8, kbase1 = (w * 64 + 256) * 8;
    const int vbase  = (w * 64) * 8;

    // Q fragments (B-operand) for two 16-q tiles
    bf16x8 bq[2][4];
#pragma unroll
    for (int qt = 0; qt < 2; ++qt)
#pragma unroll
        for (int kk = 0; kk < 4; ++kk)
            bq[qt][kk] = *(const bf16x8*)&Q2[q2base +
                (size_t)(qbase + qt * 16 + col16) * 128 + kk * 32 + quad * 8];

    f32x4 o[2][4];
    const f32x4 fzero = {0.f, 0.f, 0.f, 0.f};
#pragma unroll
    for (int qt = 0; qt < 2; ++qt)
#pragma unroll
        for (int c2 = 0; c2 < 4; ++c2) o[qt][c2] = fzero;
    float lsum[2] = {0.f, 0.f};

    // prologue: stages 0,1,2 (9 loads/thread outstanding)
    ATTN_STAGE(0,  K2sA, VtsA);
    ATTN_STAGE(32, K2sB, VtsB);
    ATTN_STAGE(64, K2sC, VtsC);

    // main: 32 stages total; at stage s: outstanding s,s+1,s+2 (9) -> VMWAIT(6)
    for (int s = 0; s < SEQ / 32 - 4; s += 4) {
        VMWAIT(6); __syncthreads();
        ATTN_STAGE((s + 3) * 32, K2sD, VtsD); ATTN_COMPUTE(K2sA, VtsA);
        VMWAIT(6); __syncthreads();
        ATTN_STAGE((s + 4) * 32, K2sA, VtsA); ATTN_COMPUTE(K2sB, VtsB);
        VMWAIT(6); __syncthreads();
        ATTN_STAGE((s + 5) * 32, K2sB, VtsB); ATTN_COMPUTE(K2sC, VtsC);
        VMWAIT(6); __syncthreads();
        ATTN_STAGE((s + 6) * 32, K2sC, VtsC); ATTN_COMPUTE(K2sD, VtsD);
    }
    // epilogue: last 4 stages; waits 6,6,3,0
    VMWAIT(6); __syncthreads();
    ATTN_STAGE(SEQ - 32, K2sD, VtsD); ATTN_COMPUTE(K2sA, VtsA);
    VMWAIT(6); __syncthreads(); ATTN_COMPUTE(K2sB, VtsB);
    VMWAIT(3); __syncthreads(); ATTN_COMPUTE(K2sC, VtsC);
    VMWAIT(0); __syncthreads(); ATTN_COMPUTE(K2sD, VtsD);

    // ---- final denominator: reduce partials across the 4 sixteens
#pragma unroll
    for (int qt = 0; qt < 2; ++qt) {
        lsum[qt] += __shfl_xor(lsum[qt], 16, 64);
        lsum[qt] += __shfl_xor(lsum[qt], 32, 64);
    }

    // ---- epilogue: o[qt][c2][r] = O^T[d = c2*16+quad*4+r][q]
#pragma unroll
    for (int qt = 0; qt < 2; ++qt) {
        const float inv = 1.0f / lsum[qt];
        const int q = qbase + qt * 16 + col16;
#pragma unroll
        for (int c2 = 0; c2 < 4; ++c2) {
#pragma unroll
            for (int r = 0; r < 4; ++r) {
                const int dd = c2 * 16 + quad * 4 + r;
                out[(((size_t)(b * 1024 + q)) * 12 + h) * 64 + dd] = o[qt][c2][r] * inv;
            }
        }
    }
}

extern "C" void kernel_launch(void* const* d_in, const int* in_sizes, int n_in,
                              void* d_out, int out_size, void* d_ws, size_t ws_size,
                              hipStream_t stream) {
    const float* x     = (const float*)d_in[0];
    const float* pos   = (const float*)d_in[1];
    const float* qkv_w = (const float*)d_in[2];
    const float* qkv_b = (const float*)d_in[3];
    const float* pq_w  = (const float*)d_in[4];
    const float* pq_b  = (const float*)d_in[5];
    const float* pk_w  = (const float*)d_in[6];
    const float* pk_b  = (const float*)d_in[7];
    float* out = (float*)d_out;

    // ws layout (shorts): [xb | posb | qkvw | pqw | pkw | Q2 | K2 | Vt]
    unsigned short* ws   = (unsigned short*)d_ws;
    unsigned short* xb   = ws;
    unsigned short* posb = xb + SZ_X;
    unsigned short* qkvw = posb + SZ_X;
    unsigned short* pqw  = qkvw + SZ_QKVW;
    unsigned short* pkw  = pqw + SZ_PW;
    unsigned short* cbuf = pkw + SZ_PW;              // = ws + CONV_TOTAL

    const size_t conv_bytes = (size_t)CONV_TOTAL * 2;
    const size_t per_batch  = (size_t)NHEAD * 1024 * 128 * 4
                            + (size_t)NHEAD * 64 * 1024 * 2;   // 7,864,320 B
    int cb = BATCH;
    while (cb > 1 && conv_bytes + (size_t)cb * per_batch > ws_size) cb >>= 1;

    unsigned short* Q2 = cbuf;
    unsigned short* K2 = Q2 + (size_t)cb * NHEAD * 1024 * 128;
    unsigned short* Vt = K2 + (size_t)cb * NHEAD * 1024 * 128;

    convert_kernel<<<(CONV_TOTAL / 4 + 255) / 256, 256, 0, stream>>>(
        x, pos, qkv_w, pq_w, pk_w, ws);

    for (int b0 = 0; b0 < BATCH; b0 += cb) {
        proj_kernel<<<dim3(cb * 8, 30), 256, 0, stream>>>(
            xb + (size_t)b0 * 1024 * 768, posb + (size_t)b0 * 1024 * 768,
            qkvw, pqw, pkw, qkv_b, pq_b, pk_b, Q2, K2, Vt);
        attn_kernel<<<dim3(cb * NHEAD, 8), 256, 0, stream>>>(Q2, K2, Vt, out, b0);
    }
}

// Round 11
// 248.275 us; speedup vs baseline: 1.1702x; 1.1702x over previous
//
#include <hip/hip_runtime.h>

#define NHEAD 12
#define BATCH 8
#define SEQ 1024
#define LOG2E 1.4426950408889634f

typedef __bf16 bf16x8 __attribute__((ext_vector_type(8)));
typedef float  f32x4  __attribute__((ext_vector_type(4)));

// global_load_lds completion is vmcnt-tracked; with distinct __shared__
// symbols the compiler emits no waits itself (R8 race) -> explicit drain.
#define WAITVM0 asm volatile("s_waitcnt vmcnt(0)" ::: "memory")

__device__ __forceinline__ unsigned short f2bf(float f) {
    union { float f; unsigned u; } v; v.f = f;
    unsigned u = v.u;
    u += 0x7fff + ((u >> 16) & 1);   // RNE
    return (unsigned short)(u >> 16);
}

__device__ __forceinline__ void gload_lds16(const void* g, void* l) {
    __builtin_amdgcn_global_load_lds(
        (const __attribute__((address_space(1))) unsigned*)g,
        (__attribute__((address_space(3))) unsigned*)l, 16, 0, 0);
}

// region sizes (floats)
#define SZ_X    6291456
#define SZ_QKVW 1769472
#define SZ_PW   589824
#define CONV_TOTAL 15532032   // x + pos + qkv_w + pq_w + pk_w

// ---------------------------------------------------------------------------
// Kernel 0: convert fp32 inputs/weights -> bf16 in workspace (once).
// ---------------------------------------------------------------------------
__global__ __launch_bounds__(256) void convert_kernel(
    const float* __restrict__ x, const float* __restrict__ pos,
    const float* __restrict__ qkv_w, const float* __restrict__ pq_w,
    const float* __restrict__ pk_w, unsigned short* __restrict__ dst)
{
    const size_t i4 = ((size_t)blockIdx.x * 256 + threadIdx.x) * 4;
    if (i4 >= CONV_TOTAL) return;
    const float* src; size_t off;
    if (i4 < SZ_X)                { src = x;     off = i4; }
    else if (i4 < 2 * SZ_X)       { src = pos;   off = i4 - SZ_X; }
    else if (i4 < 2 * SZ_X + SZ_QKVW) { src = qkv_w; off = i4 - 2 * SZ_X; }
    else if (i4 < 2 * SZ_X + SZ_QKVW + SZ_PW) { src = pq_w; off = i4 - 2 * SZ_X - SZ_QKVW; }
    else                          { src = pk_w;  off = i4 - 2 * SZ_X - SZ_QKVW - SZ_PW; }
    float4 v = *(const float4*)(src + off);
    ushort4 o;
    o.x = f2bf(v.x); o.y = f2bf(v.y); o.z = f2bf(v.z); o.w = f2bf(v.w);
    *(ushort4*)(dst + i4) = o;
}

// ---------------------------------------------------------------------------
// Kernel 1: fused projection GEMM, 128x128x32, 256 threads (4 waves x 64x64).
// R10 lesson: depth-3 prefetch == depth-1 -> latency isn't the limiter;
// occupancy is (2 blocks/CU).  This round: dbuf (32 KB LDS) +
// __launch_bounds__(256,3) (<=170 regs -> 3 waves/SIMD -> 3 blocks/CU) +
// XCD-affine 1D grid: xcd = id&7 owns a contiguous m-band (cb tiles, ~1.8 MB)
// swept over all 30 n-tiles -> A-band + B-slab stay L2-resident.
// Q2 (g0,g1) scaled by LOG2E so attn uses exp2 directly.
// ---------------------------------------------------------------------------

#define PROJ_STAGE(K0, AS, BS) do {                                          \
    const int k0_ = (K0);                                                    \
    const unsigned short* asrc_; int acol_;                                  \
    if (g == 4)                    { asrc_ = posb; acol_ = k0_; }            \
    else if (g == 3 && k0_ >= 768) { asrc_ = posb; acol_ = k0_ - 768; }      \
    else                           { asrc_ = xb;   acol_ = k0_; }            \
    gload_lds16(asrc_ + (size_t)(m0 + r0) * 768 + acol_ + q0 * 8, &AS[base0]);\
    gload_lds16(asrc_ + (size_t)(m0 + r1) * 768 + acol_ + q1 * 8, &AS[base1]);\
    const unsigned short* wsrc_; int wro_, wco_;                             \
    if (g <= 2)       { wsrc_ = qkvw; wro_ = n0;        wco_ = k0_; }        \
    else if (g == 3) {                                                       \
        if (k0_ < 768) { wsrc_ = qkvw; wro_ = n0 - 1536; wco_ = k0_; }       \
        else           { wsrc_ = pqw;  wro_ = n0 - 2304; wco_ = k0_ - 768; } \
    } else            { wsrc_ = pkw;  wro_ = n0 - 3072; wco_ = k0_; }        \
    gload_lds16(wsrc_ + (size_t)(wro_ + r0) * 768 + wco_ + q0 * 8, &BS[base0]);\
    gload_lds16(wsrc_ + (size_t)(wro_ + r1) * 768 + wco_ + q1 * 8, &BS[base1]);\
} while (0)

#define PROJ_COMPUTE(AS, BS) do {                                            \
    bf16x8 af[4], bfr[4];                                                    \
    _Pragma("unroll")                                                        \
    for (int mt = 0; mt < 4; ++mt) {                                         \
        const int rr = wm + mt * 16 + col16;                                 \
        af[mt] = *(const bf16x8*)&AS[rr * 32 + ((quad ^ ((rr >> 1) & 3)) * 8)];\
    }                                                                        \
    _Pragma("unroll")                                                        \
    for (int nt = 0; nt < 4; ++nt) {                                         \
        const int rr = wn + nt * 16 + col16;                                 \
        bfr[nt] = *(const bf16x8*)&BS[rr * 32 + ((quad ^ ((rr >> 1) & 3)) * 8)];\
    }                                                                        \
    _Pragma("unroll")                                                        \
    for (int mt = 0; mt < 4; ++mt)                                           \
        _Pragma("unroll")                                                    \
        for (int nt = 0; nt < 4; ++nt)                                       \
            acc[mt][nt] = __builtin_amdgcn_mfma_f32_16x16x32_bf16(           \
                af[mt], bfr[nt], acc[mt][nt], 0, 0, 0);                      \
} while (0)

__global__ __launch_bounds__(256, 3) void proj_kernel(
    const unsigned short* __restrict__ xb, const unsigned short* __restrict__ posb,
    const unsigned short* __restrict__ qkvw, const unsigned short* __restrict__ pqw,
    const unsigned short* __restrict__ pkw,
    const float* __restrict__ qkv_b, const float* __restrict__ pq_b,
    const float* __restrict__ pk_b,
    unsigned short* __restrict__ Q2, unsigned short* __restrict__ K2,
    unsigned short* __restrict__ Vt, int band)
{
    __shared__ unsigned short As0[128 * 32];
    __shared__ unsigned short As1[128 * 32];
    __shared__ unsigned short Bs0[128 * 32];
    __shared__ unsigned short Bs1[128 * 32];

    // XCD-affine decode: id%8 == XCD (round-robin dispatch); each XCD owns
    // m-tiles [xcd*band, xcd*band+band) and sweeps all 30 n-tiles.
    const int id  = blockIdx.x;
    const int xcd = id & 7;
    const int idx = id >> 3;
    const int nt30 = (idx / band + 18) % 30;        // g3 tiles (18..23) first
    const int m0 = (xcd * band + idx % band) * 128;
    const int n0 = nt30 * 128;
    const int g  = n0 / 768;
    const int nk = (g == 3) ? 48 : 24;              // always even

    const int tid   = threadIdx.x;
    const int lane  = tid & 63;
    const int w     = tid >> 6;
    const int wm    = (w & 1) * 64;
    const int wn    = (w >> 1) * 64;
    const int quad  = lane >> 4;
    const int col16 = lane & 15;

    // staging: 512 chunks of 16B per tile; thread handles chunks c0, c1.
    // chunk c -> row r=c>>2, LDS slot s=c&3 holds global k-seg s^((r>>1)&3).
    const int c0 = w * 64 + lane;
    const int c1 = c0 + 256;
    const int r0 = c0 >> 2, q0 = (c0 & 3) ^ ((c0 >> 3) & 3);
    const int r1 = c1 >> 2, q1 = (c1 & 3) ^ ((c1 >> 3) & 3);
    const int base0 = (w * 64) * 8;          // wave-uniform LDS short offsets
    const int base1 = (w * 64 + 256) * 8;

    f32x4 acc[4][4];
    const f32x4 fzero = {0.f, 0.f, 0.f, 0.f};
#pragma unroll
    for (int mt = 0; mt < 4; ++mt)
#pragma unroll
        for (int nt = 0; nt < 4; ++nt) acc[mt][nt] = fzero;

    PROJ_STAGE(0, As0, Bs0);

    for (int kt = 0; kt < nk; kt += 2) {
        WAITVM0;                               // buf0 DMA complete (own wave)
        __syncthreads();                       // all waves' buf0 complete
        PROJ_STAGE((kt + 1) * 32, As1, Bs1);   // in flight over compute
        PROJ_COMPUTE(As0, Bs0);

        WAITVM0;                               // buf1 DMA complete
        __syncthreads();
        if (kt + 2 < nk) PROJ_STAGE((kt + 2) * 32, As0, Bs0);
        PROJ_COMPUTE(As1, Bs1);
    }

    // ---- epilogue: C/D layout col=lane&15, row=quad*4+reg
#pragma unroll
    for (int mt = 0; mt < 4; ++mt) {
        const int mbase = m0 + wm + mt * 16 + quad * 4;
#pragma unroll
        for (int nt = 0; nt < 4; ++nt) {
            const int n = n0 + wn + nt * 16 + col16;
            if (g == 2) {
                // packed: 4 consecutive l per lane -> one 8B store
                const int b = mbase >> 10, l0 = mbase & 1023;
                const int c = n - 1536, h = c >> 6, dd = c & 63;
                ushort4 pk;
                pk.x = f2bf(acc[mt][nt][0] + qkv_b[n]);
                pk.y = f2bf(acc[mt][nt][1] + qkv_b[n]);
                pk.z = f2bf(acc[mt][nt][2] + qkv_b[n]);
                pk.w = f2bf(acc[mt][nt][3] + qkv_b[n]);
                *(ushort4*)&Vt[((size_t)(b * NHEAD + h) * 64 + dd) * 1024 + l0] = pk;
                continue;
            }
#pragma unroll
            for (int r = 0; r < 4; ++r) {
                const int m = mbase + r;
                const int b = m >> 10, l = m & 1023;   // chunk-local b
                float val = acc[mt][nt][r];
                if (g == 0) {
                    val = (val + qkv_b[n]) * LOG2E;
                    const int h = n >> 6, dd = n & 63;
                    Q2[((size_t)(b * NHEAD + h) * 1024 + l) * 128 + dd] = f2bf(val);
                } else if (g == 1) {
                    val = (val + qkv_b[n]) * (LOG2E / 48.0f);
                    const int c = n - 768, h = c >> 6, dd = c & 63;
                    Q2[((size_t)(b * NHEAD + h) * 1024 + l) * 128 + 64 + dd] = f2bf(val);
                } else if (g == 3) {
                    const int c = n - 2304;
                    val += qkv_b[n - 1536] + pq_b[c];
                    const int h = c >> 6, dd = c & 63;
                    K2[((size_t)(b * NHEAD + h) * 1024 + l) * 128 + dd] = f2bf(val);
                } else {
                    const int c = n - 3072;
                    val += pk_b[c];
                    const int h = c >> 6, dd = c & 63;
                    K2[((size_t)(b * NHEAD + h) * 1024 + l) * 128 + 64 + dd] = f2bf(val);
                }
            }
        }
    }
}

// ---------------------------------------------------------------------------
// Kernel 2: flash attention, transposed-S, exp2 softmax (log2e pre-folded
// into Q2).  Double-buffered (34 KB LDS) + __launch_bounds__(256,4)
// (regs ~124 <= 128) -> 4 blocks/CU, 16 waves (was 2 blocks / 8 waves).
// grid (cb*12, 8): id%8 == bh%8 -> all q-chunks of a bh on one XCD.
// ---------------------------------------------------------------------------

#define ATTN_STAGE(J0, KS, VS) do {                                          \
    const int j0_ = (J0);                                                    \
    gload_lds16(&K2[q2base + (size_t)(j0_ + kr0) * 128 + kc0 * 8], &KS[kbase0]);\
    gload_lds16(&K2[q2base + (size_t)(j0_ + kr1) * 128 + kc1 * 8], &KS[kbase1]);\
    gload_lds16(&Vt[vtbase + (size_t)vr * 1024 + j0_ + vc * 8],    &VS[vbase]);\
} while (0)

#define ATTN_COMPUTE(KS, VS) do {                                            \
    f32x4 st[2][2] = {{fzero, fzero}, {fzero, fzero}};                       \
    _Pragma("unroll")                                                        \
    for (int kk = 0; kk < 4; ++kk) {                                         \
        const int rrj0 = col16, rrj1 = 16 + col16;                           \
        bf16x8 kf0 = *(const bf16x8*)&KS[rrj0 * 128 + (((kk * 4 + quad) ^ (rrj0 & 15)) * 8)];\
        bf16x8 kf1 = *(const bf16x8*)&KS[rrj1 * 128 + (((kk * 4 + quad) ^ (rrj1 & 15)) * 8)];\
        _Pragma("unroll")                                                    \
        for (int qt = 0; qt < 2; ++qt) {                                     \
            st[0][qt] = __builtin_amdgcn_mfma_f32_16x16x32_bf16(kf0, bq[qt][kk], st[0][qt], 0, 0, 0);\
            st[1][qt] = __builtin_amdgcn_mfma_f32_16x16x32_bf16(kf1, bq[qt][kk], st[1][qt], 0, 0, 0);\
        }                                                                    \
    }                                                                        \
    _Pragma("unroll")                                                        \
    for (int qt = 0; qt < 2; ++qt) {                                         \
        float p0[4], p1[4], s = 0.f;                                         \
        _Pragma("unroll")                                                    \
        for (int r = 0; r < 4; ++r) {                                        \
            p0[r] = __builtin_amdgcn_exp2f(st[0][qt][r]);                    \
            p1[r] = __builtin_amdgcn_exp2f(st[1][qt][r]);                    \
            s += p0[r] + p1[r];                                              \
        }                                                                    \
        lsum[qt] += s;                                                       \
        ushort4 pk0, pk1;                                                    \
        pk0.x = f2bf(p0[0]); pk0.y = f2bf(p0[1]); pk0.z = f2bf(p0[2]); pk0.w = f2bf(p0[3]);\
        pk1.x = f2bf(p1[0]); pk1.y = f2bf(p1[1]); pk1.z = f2bf(p1[2]); pk1.w = f2bf(p1[3]);\
        *(ushort4*)&Ps[w][qt * 16 + col16][quad * 4]      = pk0;             \
        *(ushort4*)&Ps[w][qt * 16 + col16][16 + quad * 4] = pk1;             \
    }                                                                        \
    bf16x8 bp[2];                                                            \
    bp[0] = *(const bf16x8*)&Ps[w][col16][quad * 8];                         \
    bp[1] = *(const bf16x8*)&Ps[w][16 + col16][quad * 8];                    \
    _Pragma("unroll")                                                        \
    for (int c2 = 0; c2 < 4; ++c2) {                                         \
        const int rv = c2 * 16 + col16;                                      \
        bf16x8 av = *(const bf16x8*)&VS[rv * 32 + ((quad ^ ((rv >> 2) & 3)) * 8)];\
        _Pragma("unroll")                                                    \
        for (int qt = 0; qt < 2; ++qt)                                       \
            o[qt][c2] = __builtin_amdgcn_mfma_f32_16x16x32_bf16(av, bp[qt], o[qt][c2], 0, 0, 0);\
    }                                                                        \
} while (0)

__global__ __launch_bounds__(256, 4) void attn_kernel(
    const unsigned short* __restrict__ Q2, const unsigned short* __restrict__ K2,
    const unsigned short* __restrict__ Vt, float* __restrict__ out, int b0)
{
    __shared__ unsigned short K2sA[32 * 128];
    __shared__ unsigned short K2sB[32 * 128];
    __shared__ unsigned short VtsA[64 * 32];
    __shared__ unsigned short VtsB[64 * 32];
    __shared__ unsigned short Ps[4][32][40];      // per-wave P[q_local][j] (+8 pad)

    const int bh_l = blockIdx.x;
    const int b = b0 + bh_l / NHEAD, h = bh_l % NHEAD;
    const int tid   = threadIdx.x;
    const int lane  = tid & 63;
    const int w     = tid >> 6;
    const int quad  = lane >> 4;
    const int col16 = lane & 15;
    const int qbase = blockIdx.y * 128 + w * 32;

    const size_t q2base = (size_t)bh_l * 1024 * 128;
    const size_t vtbase = (size_t)bh_l * 64 * 1024;

    // staging chunk ids (16B).  K2: 512 chunks (2/thread); Vt: 256 (1/thread).
    // LDS chunk L holds global k-seg (L&15)^(r&15) [K2] / (L&3)^((L>>4)&3) [Vt].
    const int kL0 = w * 64 + lane, kL1 = kL0 + 256;
    const int kr0 = kL0 >> 4, kc0 = (kL0 & 15) ^ (kr0 & 15);
    const int kr1 = kL1 >> 4, kc1 = (kL1 & 15) ^ (kr1 & 15);
    const int vL  = w * 64 + lane;
    const int vr  = vL >> 2,  vc  = (vL & 3) ^ ((vL >> 4) & 3);
    const int kbase0 = (w * 64) * 8, kbase1 = (w * 64 + 256) * 8;
    const int vbase  = (w * 64) * 8;

    // Q fragments (B-operand) for two 16-q tiles
    bf16x8 bq[2][4];
#pragma unroll
    for (int qt = 0; qt < 2; ++qt)
#pragma unroll
        for (int kk = 0; kk < 4; ++kk)
            bq[qt][kk] = *(const bf16x8*)&Q2[q2base +
                (size_t)(qbase + qt * 16 + col16) * 128 + kk * 32 + quad * 8];

    f32x4 o[2][4];
    const f32x4 fzero = {0.f, 0.f, 0.f, 0.f};
#pragma unroll
    for (int qt = 0; qt < 2; ++qt)
#pragma unroll
        for (int c2 = 0; c2 < 4; ++c2) o[qt][c2] = fzero;
    float lsum[2] = {0.f, 0.f};

    ATTN_STAGE(0, K2sA, VtsA);

    for (int it = 0; it < SEQ / 32; it += 2) {
        WAITVM0;                                     // bufA DMA complete
        __syncthreads();
        ATTN_STAGE((it + 1) * 32, K2sB, VtsB);       // it+1 < 32 always
        ATTN_COMPUTE(K2sA, VtsA);

        WAITVM0;                                     // bufB DMA complete
        __syncthreads();
        if (it + 2 < SEQ / 32) ATTN_STAGE((it + 2) * 32, K2sA, VtsA);
        ATTN_COMPUTE(K2sB, VtsB);
    }

    // ---- final denominator: reduce partials across the 4 sixteens
#pragma unroll
    for (int qt = 0; qt < 2; ++qt) {
        lsum[qt] += __shfl_xor(lsum[qt], 16, 64);
        lsum[qt] += __shfl_xor(lsum[qt], 32, 64);
    }

    // ---- epilogue: o[qt][c2][r] = O^T[d = c2*16+quad*4+r][q]
#pragma unroll
    for (int qt = 0; qt < 2; ++qt) {
        const float inv = 1.0f / lsum[qt];
        const int q = qbase + qt * 16 + col16;
#pragma unroll
        for (int c2 = 0; c2 < 4; ++c2) {
#pragma unroll
            for (int r = 0; r < 4; ++r) {
                const int dd = c2 * 16 + quad * 4 + r;
                out[(((size_t)(b * 1024 + q)) * 12 + h) * 64 + dd] = o[qt][c2][r] * inv;
            }
        }
    }
}

extern "C" void kernel_launch(void* const* d_in, const int* in_sizes, int n_in,
                              void* d_out, int out_size, void* d_ws, size_t ws_size,
                              hipStream_t stream) {
    const float* x     = (const float*)d_in[0];
    const float* pos   = (const float*)d_in[1];
    const float* qkv_w = (const float*)d_in[2];
    const float* qkv_b = (const float*)d_in[3];
    const float* pq_w  = (const float*)d_in[4];
    const float* pq_b  = (const float*)d_in[5];
    const float* pk_w  = (const float*)d_in[6];
    const float* pk_b  = (const float*)d_in[7];
    float* out = (float*)d_out;

    // ws layout (shorts): [xb | posb | qkvw | pqw | pkw | Q2 | K2 | Vt]
    unsigned short* ws   = (unsigned short*)d_ws;
    unsigned short* xb   = ws;
    unsigned short* posb = xb + SZ_X;
    unsigned short* qkvw = posb + SZ_X;
    unsigned short* pqw  = qkvw + SZ_QKVW;
    unsigned short* pkw  = pqw + SZ_PW;
    unsigned short* cbuf = pkw + SZ_PW;              // = ws + CONV_TOTAL

    const size_t conv_bytes = (size_t)CONV_TOTAL * 2;
    const size_t per_batch  = (size_t)NHEAD * 1024 * 128 * 4
                            + (size_t)NHEAD * 64 * 1024 * 2;   // 7,864,320 B
    int cb = BATCH;
    while (cb > 1 && conv_bytes + (size_t)cb * per_batch > ws_size) cb >>= 1;

    unsigned short* Q2 = cbuf;
    unsigned short* K2 = Q2 + (size_t)cb * NHEAD * 1024 * 128;
    unsigned short* Vt = K2 + (size_t)cb * NHEAD * 1024 * 128;

    convert_kernel<<<(CONV_TOTAL / 4 + 255) / 256, 256, 0, stream>>>(
        x, pos, qkv_w, pq_w, pk_w, ws);

    for (int b0 = 0; b0 < BATCH; b0 += cb) {
        proj_kernel<<<dim3(cb * 240), 256, 0, stream>>>(
            xb + (size_t)b0 * 1024 * 768, posb + (size_t)b0 * 1024 * 768,
            qkvw, pqw, pkw, qkv_b, pq_b, pk_b, Q2, K2, Vt, cb);
        attn_kernel<<<dim3(cb * NHEAD, 8), 256, 0, stream>>>(Q2, K2, Vt, out, b0);
    }
}

// Round 12
// 243.586 us; speedup vs baseline: 1.1928x; 1.0192x over previous
//
#include <hip/hip_runtime.h>
#include <hip/hip_bf16.h>

#define NHEAD 12
#define BATCH 8
#define SEQ 1024
#define LOG2E 1.4426950408889634f

typedef __bf16 bf16x8 __attribute__((ext_vector_type(8)));
typedef float  f32x4  __attribute__((ext_vector_type(4)));

// global_load_lds completion is vmcnt-tracked; with distinct __shared__
// symbols the compiler emits no waits itself (R8 race) -> explicit drain.
#define WAITVM0 asm volatile("s_waitcnt vmcnt(0)" ::: "memory")

#define MFMA(A, B, C) __builtin_amdgcn_mfma_f32_16x16x32_bf16(A, B, C, 0, 0, 0)

__device__ __forceinline__ unsigned short f2bf(float f) {
    union { float f; unsigned u; } v; v.f = f;
    unsigned u = v.u;
    u += 0x7fff + ((u >> 16) & 1);   // RNE
    return (unsigned short)(u >> 16);
}

__device__ __forceinline__ unsigned pkbf(float a, float b) {
    union { __hip_bfloat162 h; unsigned u; } cv;
    cv.h = __float22bfloat162_rn(make_float2(a, b));   // RNE, packed cvt
    return cv.u;
}

__device__ __forceinline__ void gload_lds16(const void* g, void* l) {
    __builtin_amdgcn_global_load_lds(
        (const __attribute__((address_space(1))) unsigned*)g,
        (__attribute__((address_space(3))) unsigned*)l, 16, 0, 0);
}

// region sizes (floats)
#define SZ_X    6291456
#define SZ_QKVW 1769472
#define SZ_PW   589824
#define CONV_TOTAL 15532032   // x + pos + qkv_w + pq_w + pk_w

// ---------------------------------------------------------------------------
// Kernel 0: convert fp32 inputs/weights -> bf16 in workspace (once).
// ---------------------------------------------------------------------------
__global__ __launch_bounds__(256) void convert_kernel(
    const float* __restrict__ x, const float* __restrict__ pos,
    const float* __restrict__ qkv_w, const float* __restrict__ pq_w,
    const float* __restrict__ pk_w, unsigned short* __restrict__ dst)
{
    const size_t i4 = ((size_t)blockIdx.x * 256 + threadIdx.x) * 4;
    if (i4 >= CONV_TOTAL) return;
    const float* src; size_t off;
    if (i4 < SZ_X)                { src = x;     off = i4; }
    else if (i4 < 2 * SZ_X)       { src = pos;   off = i4 - SZ_X; }
    else if (i4 < 2 * SZ_X + SZ_QKVW) { src = qkv_w; off = i4 - 2 * SZ_X; }
    else if (i4 < 2 * SZ_X + SZ_QKVW + SZ_PW) { src = pq_w; off = i4 - 2 * SZ_X - SZ_QKVW; }
    else                          { src = pk_w;  off = i4 - 2 * SZ_X - SZ_QKVW - SZ_PW; }
    float4 v = *(const float4*)(src + off);
    ushort4 o;
    o.x = f2bf(v.x); o.y = f2bf(v.y); o.z = f2bf(v.z); o.w = f2bf(v.w);
    *(ushort4*)(dst + i4) = o;
}

// ---------------------------------------------------------------------------
// Kernel 1: fused projection GEMM — UNCHANGED from R11 (101 µs, known good).
// 128x128x32, 4 waves, dbuf distinct symbols, WAITVM0+barrier per stage,
// XCD-affine m-bands, launch_bounds(256,3).
// ---------------------------------------------------------------------------

#define PROJ_STAGE(K0, AS, BS) do {                                          \
    const int k0_ = (K0);                                                    \
    const unsigned short* asrc_; int acol_;                                  \
    if (g == 4)                    { asrc_ = posb; acol_ = k0_; }            \
    else if (g == 3 && k0_ >= 768) { asrc_ = posb; acol_ = k0_ - 768; }      \
    else                           { asrc_ = xb;   acol_ = k0_; }            \
    gload_lds16(asrc_ + (size_t)(m0 + r0) * 768 + acol_ + q0 * 8, &AS[base0]);\
    gload_lds16(asrc_ + (size_t)(m0 + r1) * 768 + acol_ + q1 * 8, &AS[base1]);\
    const unsigned short* wsrc_; int wro_, wco_;                             \
    if (g <= 2)       { wsrc_ = qkvw; wro_ = n0;        wco_ = k0_; }        \
    else if (g == 3) {                                                       \
        if (k0_ < 768) { wsrc_ = qkvw; wro_ = n0 - 1536; wco_ = k0_; }       \
        else           { wsrc_ = pqw;  wro_ = n0 - 2304; wco_ = k0_ - 768; } \
    } else            { wsrc_ = pkw;  wro_ = n0 - 3072; wco_ = k0_; }        \
    gload_lds16(wsrc_ + (size_t)(wro_ + r0) * 768 + wco_ + q0 * 8, &BS[base0]);\
    gload_lds16(wsrc_ + (size_t)(wro_ + r1) * 768 + wco_ + q1 * 8, &BS[base1]);\
} while (0)

#define PROJ_COMPUTE(AS, BS) do {                                            \
    bf16x8 af[4], bfr[4];                                                    \
    _Pragma("unroll")                                                        \
    for (int mt = 0; mt < 4; ++mt) {                                         \
        const int rr = wm + mt * 16 + col16;                                 \
        af[mt] = *(const bf16x8*)&AS[rr * 32 + ((quad ^ ((rr >> 1) & 3)) * 8)];\
    }                                                                        \
    _Pragma("unroll")                                                        \
    for (int nt = 0; nt < 4; ++nt) {                                         \
        const int rr = wn + nt * 16 + col16;                                 \
        bfr[nt] = *(const bf16x8*)&BS[rr * 32 + ((quad ^ ((rr >> 1) & 3)) * 8)];\
    }                                                                        \
    _Pragma("unroll")                                                        \
    for (int mt = 0; mt < 4; ++mt)                                           \
        _Pragma("unroll")                                                    \
        for (int nt = 0; nt < 4; ++nt)                                       \
            acc[mt][nt] = MFMA(af[mt], bfr[nt], acc[mt][nt]);                \
} while (0)

__global__ __launch_bounds__(256, 3) void proj_kernel(
    const unsigned short* __restrict__ xb, const unsigned short* __restrict__ posb,
    const unsigned short* __restrict__ qkvw, const unsigned short* __restrict__ pqw,
    const unsigned short* __restrict__ pkw,
    const float* __restrict__ qkv_b, const float* __restrict__ pq_b,
    const float* __restrict__ pk_b,
    unsigned short* __restrict__ Q2, unsigned short* __restrict__ K2,
    unsigned short* __restrict__ Vt, int band)
{
    __shared__ unsigned short As0[128 * 32];
    __shared__ unsigned short As1[128 * 32];
    __shared__ unsigned short Bs0[128 * 32];
    __shared__ unsigned short Bs1[128 * 32];

    const int id  = blockIdx.x;
    const int xcd = id & 7;
    const int idx = id >> 3;
    const int nt30 = (idx / band + 18) % 30;        // g3 tiles (18..23) first
    const int m0 = (xcd * band + idx % band) * 128;
    const int n0 = nt30 * 128;
    const int g  = n0 / 768;
    const int nk = (g == 3) ? 48 : 24;              // always even

    const int tid   = threadIdx.x;
    const int lane  = tid & 63;
    const int w     = tid >> 6;
    const int wm    = (w & 1) * 64;
    const int wn    = (w >> 1) * 64;
    const int quad  = lane >> 4;
    const int col16 = lane & 15;

    const int c0 = w * 64 + lane;
    const int c1 = c0 + 256;
    const int r0 = c0 >> 2, q0 = (c0 & 3) ^ ((c0 >> 3) & 3);
    const int r1 = c1 >> 2, q1 = (c1 & 3) ^ ((c1 >> 3) & 3);
    const int base0 = (w * 64) * 8;
    const int base1 = (w * 64 + 256) * 8;

    f32x4 acc[4][4];
    const f32x4 fzero = {0.f, 0.f, 0.f, 0.f};
#pragma unroll
    for (int mt = 0; mt < 4; ++mt)
#pragma unroll
        for (int nt = 0; nt < 4; ++nt) acc[mt][nt] = fzero;

    PROJ_STAGE(0, As0, Bs0);

    for (int kt = 0; kt < nk; kt += 2) {
        WAITVM0;
        __syncthreads();
        PROJ_STAGE((kt + 1) * 32, As1, Bs1);
        PROJ_COMPUTE(As0, Bs0);

        WAITVM0;
        __syncthreads();
        if (kt + 2 < nk) PROJ_STAGE((kt + 2) * 32, As0, Bs0);
        PROJ_COMPUTE(As1, Bs1);
    }

#pragma unroll
    for (int mt = 0; mt < 4; ++mt) {
        const int mbase = m0 + wm + mt * 16 + quad * 4;
#pragma unroll
        for (int nt = 0; nt < 4; ++nt) {
            const int n = n0 + wn + nt * 16 + col16;
            if (g == 2) {
                const int b = mbase >> 10, l0 = mbase & 1023;
                const int c = n - 1536, h = c >> 6, dd = c & 63;
                const float bias = qkv_b[n];
                uint2 pk;
                pk.x = pkbf(acc[mt][nt][0] + bias, acc[mt][nt][1] + bias);
                pk.y = pkbf(acc[mt][nt][2] + bias, acc[mt][nt][3] + bias);
                *(uint2*)&Vt[((size_t)(b * NHEAD + h) * 64 + dd) * 1024 + l0] = pk;
                continue;
            }
#pragma unroll
            for (int r = 0; r < 4; ++r) {
                const int m = mbase + r;
                const int b = m >> 10, l = m & 1023;
                float val = acc[mt][nt][r];
                if (g == 0) {
                    val = (val + qkv_b[n]) * LOG2E;
                    const int h = n >> 6, dd = n & 63;
                    Q2[((size_t)(b * NHEAD + h) * 1024 + l) * 128 + dd] = f2bf(val);
                } else if (g == 1) {
                    val = (val + qkv_b[n]) * (LOG2E / 48.0f);
                    const int c = n - 768, h = c >> 6, dd = c & 63;
                    Q2[((size_t)(b * NHEAD + h) * 1024 + l) * 128 + 64 + dd] = f2bf(val);
                } else if (g == 3) {
                    const int c = n - 2304;
                    val += qkv_b[n - 1536] + pq_b[c];
                    const int h = c >> 6, dd = c & 63;
                    K2[((size_t)(b * NHEAD + h) * 1024 + l) * 128 + dd] = f2bf(val);
                } else {
                    const int c = n - 3072;
                    val += pk_b[c];
                    const int h = c >> 6, dd = c & 63;
                    K2[((size_t)(b * NHEAD + h) * 1024 + l) * 128 + 64 + dd] = f2bf(val);
                }
            }
        }
    }
}

// ---------------------------------------------------------------------------
// Kernel 2: flash attention with LAG-1 PV pipelining.
// Per phase i (ONE barrier, ONE vmcnt wait):
//   VMWAIT(0); barrier; STAGE(i+1); PV_{i-1}(Vt[i-1], Ps[i-1]); QK_i; softmax->Ps[i]
// No-rescale softmax (pure sum) makes O accumulation order-free, so PV can lag.
// Buffers: K2s x2 (QK i%2 vs DMA (i+1)%2 disjoint), Vt x3 (DMA (i+1)%3 vs
// PV (i-1)%3 disjoint), Ps x2 (RAW one phase apart).  x6 unroll for
// compile-time symbols (keeps compiler from alias-pessimizing: R7 lesson).
// LDS 48 KB -> 3 blocks/CU.  grid (cb*12, 8), bh%8 XCD-affine.
// ---------------------------------------------------------------------------

#define ATTN_STG(J0, KS, VS) do {                                            \
    const int j0_ = (J0);                                                    \
    gload_lds16(&K2[q2base + (size_t)(j0_ + kr0) * 128 + kc0 * 8], &KS[kbase0]);\
    gload_lds16(&K2[q2base + (size_t)(j0_ + kr1) * 128 + kc1 * 8], &KS[kbase1]);\
    gload_lds16(&Vt[vtbase + (size_t)vr * 1024 + j0_ + vc * 8],    &VS[vbase]);\
} while (0)

#define ATTN_PV(VS, PSR) do {                                                \
    bf16x8 bp0 = *(const bf16x8*)&PSR[w][col16][quad * 8];                   \
    bf16x8 bp1 = *(const bf16x8*)&PSR[w][16 + col16][quad * 8];              \
    _Pragma("unroll")                                                        \
    for (int c2 = 0; c2 < 4; ++c2) {                                         \
        const int rv = c2 * 16 + col16;                                      \
        bf16x8 av = *(const bf16x8*)&VS[rv * 32 + ((quad ^ ((rv >> 2) & 3)) * 8)];\
        o[0][c2] = MFMA(av, bp0, o[0][c2]);                                  \
        o[1][c2] = MFMA(av, bp1, o[1][c2]);                                  \
    }                                                                        \
} while (0)

#define ATTN_QK(KS, PSW) do {                                                \
    f32x4 st[2][2] = {{fzero, fzero}, {fzero, fzero}};                       \
    _Pragma("unroll")                                                        \
    for (int kk = 0; kk < 4; ++kk) {                                         \
        const int rrj0 = col16, rrj1 = 16 + col16;                           \
        bf16x8 kf0 = *(const bf16x8*)&KS[rrj0 * 128 + (((kk * 4 + quad) ^ (rrj0 & 15)) * 8)];\
        bf16x8 kf1 = *(const bf16x8*)&KS[rrj1 * 128 + (((kk * 4 + quad) ^ (rrj1 & 15)) * 8)];\
        _Pragma("unroll")                                                    \
        for (int qt = 0; qt < 2; ++qt) {                                     \
            st[0][qt] = MFMA(kf0, bq[qt][kk], st[0][qt]);                    \
            st[1][qt] = MFMA(kf1, bq[qt][kk], st[1][qt]);                    \
        }                                                                    \
    }                                                                        \
    _Pragma("unroll")                                                        \
    for (int qt = 0; qt < 2; ++qt) {                                         \
        float p0[4], p1[4], s = 0.f;                                         \
        _Pragma("unroll")                                                    \
        for (int r = 0; r < 4; ++r) {                                        \
            p0[r] = __builtin_amdgcn_exp2f(st[0][qt][r]);                    \
            p1[r] = __builtin_amdgcn_exp2f(st[1][qt][r]);                    \
            s += p0[r] + p1[r];                                              \
        }                                                                    \
        lsum[qt] += s;                                                       \
        uint2 w0, w1;                                                        \
        w0.x = pkbf(p0[0], p0[1]); w0.y = pkbf(p0[2], p0[3]);                \
        w1.x = pkbf(p1[0], p1[1]); w1.y = pkbf(p1[2], p1[3]);                \
        *(uint2*)&PSW[w][qt * 16 + col16][quad * 4]      = w0;               \
        *(uint2*)&PSW[w][qt * 16 + col16][16 + quad * 4] = w1;               \
    }                                                                        \
} while (0)

// phase: DOPV/DOST are compile-time 0/1
#define ATTN_PHASE(J, KQK, KST, VPV, VST, PSW, PSR, DOPV, DOST) do {         \
    WAITVM0;                                                                 \
    __syncthreads();                                                         \
    if (DOST) ATTN_STG(((J) + 1) * 32, KST, VST);                            \
    if (DOPV) ATTN_PV(VPV, PSR);                                             \
    ATTN_QK(KQK, PSW);                                                       \
} while (0)

__global__ __launch_bounds__(256, 3) void attn_kernel(
    const unsigned short* __restrict__ Q2, const unsigned short* __restrict__ K2,
    const unsigned short* __restrict__ Vt, float* __restrict__ out, int b0)
{
    __shared__ unsigned short K2sA[32 * 128];
    __shared__ unsigned short K2sB[32 * 128];
    __shared__ unsigned short VtX[64 * 32];
    __shared__ unsigned short VtY[64 * 32];
    __shared__ unsigned short VtZ[64 * 32];
    __shared__ unsigned short Ps0[4][32][40];
    __shared__ unsigned short Ps1[4][32][40];

    const int bh_l = blockIdx.x;
    const int b = b0 + bh_l / NHEAD, h = bh_l % NHEAD;
    const int tid   = threadIdx.x;
    const int lane  = tid & 63;
    const int w     = tid >> 6;
    const int quad  = lane >> 4;
    const int col16 = lane & 15;
    const int qbase = blockIdx.y * 128 + w * 32;

    const size_t q2base = (size_t)bh_l * 1024 * 128;
    const size_t vtbase = (size_t)bh_l * 64 * 1024;

    const int kL0 = w * 64 + lane, kL1 = kL0 + 256;
    const int kr0 = kL0 >> 4, kc0 = (kL0 & 15) ^ (kr0 & 15);
    const int kr1 = kL1 >> 4, kc1 = (kL1 & 15) ^ (kr1 & 15);
    const int vL  = w * 64 + lane;
    const int vr  = vL >> 2,  vc  = (vL & 3) ^ ((vL >> 4) & 3);
    const int kbase0 = (w * 64) * 8, kbase1 = (w * 64 + 256) * 8;
    const int vbase  = (w * 64) * 8;

    bf16x8 bq[2][4];
#pragma unroll
    for (int qt = 0; qt < 2; ++qt)
#pragma unroll
        for (int kk = 0; kk < 4; ++kk)
            bq[qt][kk] = *(const bf16x8*)&Q2[q2base +
                (size_t)(qbase + qt * 16 + col16) * 128 + kk * 32 + quad * 8];

    f32x4 o[2][4];
    const f32x4 fzero = {0.f, 0.f, 0.f, 0.f};
#pragma unroll
    for (int qt = 0; qt < 2; ++qt)
#pragma unroll
        for (int c2 = 0; c2 < 4; ++c2) o[qt][c2] = fzero;
    float lsum[2] = {0.f, 0.f};

    // prologue: stage 0 -> (K2sA, VtX)
    ATTN_STG(0, K2sA, VtX);

    // phase 0 (pattern J%6==0, no PV): stage 1 -> (K2sB, VtY); QK A -> Ps0
    ATTN_PHASE(0, K2sA, K2sB, VtZ, VtY, Ps0, Ps1, 0, 1);

    // phases 1..30 in 5 trips of 6 (patterns J%6 = 1,2,3,4,5,0)
    for (int j = 1; j < 31; j += 6) {
        ATTN_PHASE(j + 0, K2sB, K2sA, VtX, VtZ, Ps1, Ps0, 1, 1);
        ATTN_PHASE(j + 1, K2sA, K2sB, VtY, VtX, Ps0, Ps1, 1, 1);
        ATTN_PHASE(j + 2, K2sB, K2sA, VtZ, VtY, Ps1, Ps0, 1, 1);
        ATTN_PHASE(j + 3, K2sA, K2sB, VtX, VtZ, Ps0, Ps1, 1, 1);
        ATTN_PHASE(j + 4, K2sB, K2sA, VtY, VtX, Ps1, Ps0, 1, 1);
        ATTN_PHASE(j + 5, K2sA, K2sB, VtZ, VtY, Ps0, Ps1, 1, 1);
    }

    // phase 31 (pattern J%6==1, no stage): PV_30 (VtX, Ps0); QK B -> Ps1
    ATTN_PHASE(31, K2sB, K2sA, VtX, VtZ, Ps1, Ps0, 1, 0);

    // final PV_31: Vt[31%3=1]=VtY, Ps1 (staged at phase 30, synced at 31)
    ATTN_PV(VtY, Ps1);

    // ---- final denominator: reduce partials across the 4 sixteens
#pragma unroll
    for (int qt = 0; qt < 2; ++qt) {
        lsum[qt] += __shfl_xor(lsum[qt], 16, 64);
        lsum[qt] += __shfl_xor(lsum[qt], 32, 64);
    }

    // ---- epilogue: o[qt][c2][r] = O^T[d = c2*16+quad*4+r][q]
#pragma unroll
    for (int qt = 0; qt < 2; ++qt) {
        const float inv = 1.0f / lsum[qt];
        const int q = qbase + qt * 16 + col16;
#pragma unroll
        for (int c2 = 0; c2 < 4; ++c2) {
#pragma unroll
            for (int r = 0; r < 4; ++r) {
                const int dd = c2 * 16 + quad * 4 + r;
                out[(((size_t)(b * 1024 + q)) * 12 + h) * 64 + dd] = o[qt][c2][r] * inv;
            }
        }
    }
}

extern "C" void kernel_launch(void* const* d_in, const int* in_sizes, int n_in,
                              void* d_out, int out_size, void* d_ws, size_t ws_size,
                              hipStream_t stream) {
    const float* x     = (const float*)d_in[0];
    const float* pos   = (const float*)d_in[1];
    const float* qkv_w = (const float*)d_in[2];
    const float* qkv_b = (const float*)d_in[3];
    const float* pq_w  = (const float*)d_in[4];
    const float* pq_b  = (const float*)d_in[5];
    const float* pk_w  = (const float*)d_in[6];
    const float* pk_b  = (const float*)d_in[7];
    float* out = (float*)d_out;

    // ws layout (shorts): [xb | posb | qkvw | pqw | pkw | Q2 | K2 | Vt]
    unsigned short* ws   = (unsigned short*)d_ws;
    unsigned short* xb   = ws;
    unsigned short* posb = xb + SZ_X;
    unsigned short* qkvw = posb + SZ_X;
    unsigned short* pqw  = qkvw + SZ_QKVW;
    unsigned short* pkw  = pqw + SZ_PW;
    unsigned short* cbuf = pkw + SZ_PW;              // = ws + CONV_TOTAL

    const size_t conv_bytes = (size_t)CONV_TOTAL * 2;
    const size_t per_batch  = (size_t)NHEAD * 1024 * 128 * 4
                            + (size_t)NHEAD * 64 * 1024 * 2;   // 7,864,320 B
    int cb = BATCH;
    while (cb > 1 && conv_bytes + (size_t)cb * per_batch > ws_size) cb >>= 1;

    unsigned short* Q2 = cbuf;
    unsigned short* K2 = Q2 + (size_t)cb * NHEAD * 1024 * 128;
    unsigned short* Vt = K2 + (size_t)cb * NHEAD * 1024 * 128;

    convert_kernel<<<(CONV_TOTAL / 4 + 255) / 256, 256, 0, stream>>>(
        x, pos, qkv_w, pq_w, pk_w, ws);

    for (int b0 = 0; b0 < BATCH; b0 += cb) {
        proj_kernel<<<dim3(cb * 240), 256, 0, stream>>>(
            xb + (size_t)b0 * 1024 * 768, posb + (size_t)b0 * 1024 * 768,
            qkvw, pqw, pkw, qkv_b, pq_b, pk_b, Q2, K2, Vt, cb);
        attn_kernel<<<dim3(cb * NHEAD, 8), 256, 0, stream>>>(Q2, K2, Vt, out, b0);
    }
}